// Round 2
// baseline (665.971 us; speedup 1.0000x reference)
//
#include <hip/hip_runtime.h>
#include <hip/hip_bf16.h>
#include <math.h>

#define HN 64
#define KNN 15

__device__ __forceinline__ unsigned fenc(float f){
  unsigned u = __float_as_uint(f);
  return (u & 0x80000000u) ? ~u : (u | 0x80000000u);
}
__device__ __forceinline__ float fdec(unsigned u){
  return (u & 0x80000000u) ? __uint_as_float(u & 0x7fffffffu) : __uint_as_float(~u);
}

// Detect whether edge_index is stored as int64 (reference dtype) or int32.
__global__ void k_flag(const void* ei, int* flag, int n){
  __shared__ int ok[256];
  int t = threadIdx.x;
  long long v = ((const long long*)ei)[t];
  ok[t] = (v >= 0 && v < (long long)n) ? 1 : 0;
  __syncthreads();
  for (int off = 128; off > 0; off >>= 1){
    if (t < off) ok[t] &= ok[t + off];
    __syncthreads();
  }
  if (t == 0) *flag = ok[0];
}

__device__ __forceinline__ void edge_rc(const void* ei, int is64, int E, int e, int& r, int& c){
  if (is64){
    r = (int)((const long long*)ei)[e];
    c = (int)((const long long*)ei)[E + e];
  } else {
    r = ((const int*)ei)[e];
    c = ((const int*)ei)[E + e];
  }
}

__global__ void k_sq(const float* __restrict__ x, float* __restrict__ sq, int n){
  int i = blockIdx.x * 256 + threadIdx.x;
  if (i >= n) return;
  float a = x[i*3], b = x[i*3+1], c = x[i*3+2];
  sq[i] = a*a + b*b + c*c;
}

// Block per node: full-N distance row in LDS, 15 iterative argmins (index tie-break).
__global__ void k_knn(const float* __restrict__ x, const float* __restrict__ sq,
                      int* __restrict__ knn_cols, int n){
  __shared__ float d2s[4096];
  __shared__ float rv[256];
  __shared__ int   ri[256];
  int i = blockIdx.x;
  int t = threadIdx.x;
  float xi0 = x[i*3], xi1 = x[i*3+1], xi2 = x[i*3+2];
  float sqi = sq[i];
  for (int j = t; j < n; j += 256){
    float dot = xi0*x[j*3] + xi1*x[j*3+1] + xi2*x[j*3+2];
    float d2 = (sqi - 2.0f*dot) + sq[j];
    if (j == i) d2 = INFINITY;
    d2s[j] = d2;
  }
  __syncthreads();
  for (int m = 0; m < KNN; ++m){
    float bv = INFINITY; int bi = n;
    for (int j = t; j < n; j += 256){
      float v = d2s[j];
      if (v < bv || (v == bv && j < bi)){ bv = v; bi = j; }
    }
    rv[t] = bv; ri[t] = bi;
    __syncthreads();
    for (int off = 128; off > 0; off >>= 1){
      if (t < off){
        float v2 = rv[t+off]; int i2 = ri[t+off];
        if (v2 < rv[t] || (v2 == rv[t] && i2 < ri[t])){ rv[t] = v2; ri[t] = i2; }
      }
      __syncthreads();
    }
    if (t == 0){
      knn_cols[i*KNN + m] = ri[0];
      d2s[ri[0]] = INFINITY;
    }
    __syncthreads();
  }
}

// y = x @ W_theta^T   [N,64]
__global__ void k_y(const float* __restrict__ x, const float* __restrict__ Wt,
                    float* __restrict__ y, int n){
  int gid = blockIdx.x * 256 + threadIdx.x;
  if (gid >= n * HN) return;
  int nn = gid >> 6, h = gid & 63;
  float acc = x[nn*3] * Wt[h*3] + x[nn*3+1] * Wt[h*3+1] + x[nn*3+2] * Wt[h*3+2];
  y[gid] = acc;
}

// per (extended-edge, feature) atomic min of y[col][h] into minu[row][h]
__global__ void k_minedge(const void* ei, const int* flag, const int* __restrict__ knn_cols,
                          const float* __restrict__ y, unsigned* __restrict__ minu,
                          int E, int n){
  int gid = blockIdx.x * 256 + threadIdx.x;
  int total = (E + n*KNN) * HN;
  if (gid >= total) return;
  int e = gid >> 6, h = gid & 63;
  int r, c;
  if (e < E){
    edge_rc(ei, *flag, E, e, r, c);
  } else {
    int m = e - E;
    r = m / KNN;
    c = knn_cols[m];
  }
  atomicMin(&minu[r*HN + h], fenc(y[c*HN + h]));
}

// in-place: agg = y + b_theta - min   (uint-decoded)
__global__ void k_agg(const float* __restrict__ y, const float* __restrict__ bt,
                      unsigned* __restrict__ minu, int n){
  int gid = blockIdx.x * 256 + threadIdx.x;
  if (gid >= n * HN) return;
  int h = gid & 63;
  float mn = fdec(minu[gid]);
  float v = y[gid] + bt[h] - mn;
  ((float*)minu)[gid] = v;
}

// feats = agg @ W_phi^T + b_phi
__global__ void k_feats(const float* __restrict__ agg, const float* __restrict__ Wp,
                        const float* __restrict__ bp, float* __restrict__ feats, int n){
  int gid = blockIdx.x * 256 + threadIdx.x;
  if (gid >= n * HN) return;
  int nn = gid >> 6, h = gid & 63;
  float acc = bp[h];
  #pragma unroll 8
  for (int c = 0; c < HN; ++c) acc += agg[nn*HN + c] * Wp[h*HN + c];
  feats[gid] = acc;
}

// q = feats @ W_q^T ; kf = feats @ W_k^T
__global__ void k_qk(const float* __restrict__ feats, const float* __restrict__ Wq,
                     const float* __restrict__ Wk, float* __restrict__ q,
                     float* __restrict__ kf, int n){
  int gid = blockIdx.x * 256 + threadIdx.x;
  if (gid >= n * HN) return;
  int nn = gid >> 6, h = gid & 63;
  float aq = 0.f, ak = 0.f;
  #pragma unroll 8
  for (int c = 0; c < HN; ++c){
    float f = feats[nn*HN + c];
    aq += f * Wq[h*HN + c];
    ak += f * Wk[h*HN + c];
  }
  q[gid] = aq; kf[gid] = ak;
}

// attn[e] = dot64(q[row], kf[col]) ; also rowmax + row count
__global__ void k_attn(const void* ei, const int* flag, const float* __restrict__ q,
                       const float* __restrict__ kf, float* __restrict__ attn,
                       unsigned* __restrict__ rowmax, int* __restrict__ cnt, int E){
  int e = blockIdx.x * 256 + threadIdx.x;
  if (e >= E) return;
  int r, c;
  edge_rc(ei, *flag, E, e, r, c);
  const float4* qr = (const float4*)(q + r*HN);
  const float4* kc = (const float4*)(kf + c*HN);
  float acc = 0.f;
  #pragma unroll
  for (int m = 0; m < HN/4; ++m){
    float4 a = qr[m], b = kc[m];
    acc += a.x*b.x + a.y*b.y + a.z*b.z + a.w*b.w;
  }
  attn[e] = acc;
  atomicMax(&rowmax[r], fenc(acc));
  atomicAdd(&cnt[r], 1);
}

// exclusive prefix sum over 4096 counts, single block of 1024
__global__ void k_scan(const int* __restrict__ cnt, int* __restrict__ ptr, int n){
  __shared__ int part[1024];
  int t = threadIdx.x;
  int base = t * 4;
  int a0 = cnt[base], a1 = cnt[base+1], a2 = cnt[base+2], a3 = cnt[base+3];
  int s = a0 + a1 + a2 + a3;
  part[t] = s;
  __syncthreads();
  for (int off = 1; off < 1024; off <<= 1){
    int v = (t >= off) ? part[t - off] : 0;
    __syncthreads();
    part[t] += v;
    __syncthreads();
  }
  int excl = part[t] - s;
  ptr[base]   = excl;
  ptr[base+1] = excl + a0;
  ptr[base+2] = excl + a0 + a1;
  ptr[base+3] = excl + a0 + a1 + a2;
  if (t == 1023) ptr[n] = part[1023];
}

__global__ void k_exp(const void* ei, const int* flag, const float* __restrict__ attn,
                      const unsigned* __restrict__ rowmax, float* __restrict__ scores,
                      float* __restrict__ rowsum, int E){
  int e = blockIdx.x * 256 + threadIdx.x;
  if (e >= E) return;
  int r, c;
  edge_rc(ei, *flag, E, e, r, c);
  float ex = expf(attn[e] - fdec(rowmax[r]));
  scores[e] = ex;
  atomicAdd(&rowsum[r], ex);
}

// Fill CSR of S (normalized scores) and dense A^T counts.
__global__ void k_csr(const void* ei, const int* flag, const float* __restrict__ scores,
                      const float* __restrict__ rowsum, const int* __restrict__ ptr,
                      int* __restrict__ fill, int* __restrict__ csr_col,
                      float* __restrict__ csr_val, float* __restrict__ AT, int E, int n){
  int e = blockIdx.x * 256 + threadIdx.x;
  if (e >= E) return;
  int r, c;
  edge_rc(ei, *flag, E, e, r, c);
  int pos = ptr[r] + atomicAdd(&fill[r], 1);
  csr_col[pos] = c;
  csr_val[pos] = scores[e] / rowsum[r];
  atomicAdd(&AT[(size_t)c * n + r], 1.0f);
}

// out[i,:] = sum_p csr_val[p] * M[csr_col[p], :]   (block per row, 16 f32 acc/thread)
__global__ void k_spmm(const int* __restrict__ ptr, const int* __restrict__ col,
                       const float* __restrict__ val, const float* __restrict__ M,
                       float* __restrict__ out, int n){
  int i = blockIdx.x;
  int t = threadIdx.x;   // 256
  float4 acc0 = {0,0,0,0}, acc1 = {0,0,0,0}, acc2 = {0,0,0,0}, acc3 = {0,0,0,0};
  int beg = ptr[i], end = ptr[i+1];
  for (int p = beg; p < end; ++p){
    int k = col[p];
    float v = val[p];
    const float4* row = (const float4*)(M + (size_t)k * n);
    float4 a;
    a = row[0*256 + t]; acc0.x += v*a.x; acc0.y += v*a.y; acc0.z += v*a.z; acc0.w += v*a.w;
    a = row[1*256 + t]; acc1.x += v*a.x; acc1.y += v*a.y; acc1.z += v*a.z; acc1.w += v*a.w;
    a = row[2*256 + t]; acc2.x += v*a.x; acc2.y += v*a.y; acc2.z += v*a.z; acc2.w += v*a.w;
    a = row[3*256 + t]; acc3.x += v*a.x; acc3.y += v*a.y; acc3.z += v*a.z; acc3.w += v*a.w;
  }
  float4* o = (float4*)(out + (size_t)i * n);
  o[0*256 + t] = acc0;
  o[1*256 + t] = acc1;
  o[2*256 + t] = acc2;
  o[3*256 + t] = acc3;
}

// tiled transpose: out[j,i] = in[i,j]
__global__ void k_tr(const float* __restrict__ in, float* __restrict__ out, int n){
  __shared__ float tile[32][33];
  int bx = blockIdx.x * 32, by = blockIdx.y * 32;
  int tx = threadIdx.x, ty = threadIdx.y;
  #pragma unroll
  for (int i = 0; i < 32; i += 8)
    tile[ty + i][tx] = in[(size_t)(by + ty + i) * n + bx + tx];
  __syncthreads();
  #pragma unroll
  for (int i = 0; i < 32; i += 8)
    out[(size_t)(bx + ty + i) * n + by + tx] = tile[tx][ty + i];
}

extern "C" void kernel_launch(void* const* d_in, const int* in_sizes, int n_in,
                              void* d_out, int out_size, void* d_ws, size_t ws_size,
                              hipStream_t stream) {
  const float* x   = (const float*)d_in[0];
  const void*  ei  = d_in[1];
  const float* Wt  = (const float*)d_in[2];
  const float* bt  = (const float*)d_in[3];
  const float* Wp  = (const float*)d_in[4];
  const float* bp  = (const float*)d_in[5];
  const float* Wq  = (const float*)d_in[6];
  const float* Wk  = (const float*)d_in[7];
  float* out = (float*)d_out;

  const int N = in_sizes[0] / 3;         // 4096
  const int E = in_sizes[1] / 2;         // 65536
  const size_t NN = (size_t)N * N;

  // bump allocator on workspace (256B aligned)
  char* p = (char*)d_ws;
  auto alloc = [&](size_t bytes) -> void* {
    void* r = (void*)p;
    p += (bytes + 255) & ~(size_t)255;
    return r;
  };
  float*    WORK    = (float*)   alloc(NN * 4);          // A^T, later U
  float*    y       = (float*)   alloc((size_t)N*HN*4);
  unsigned* minu    = (unsigned*)alloc((size_t)N*HN*4);
  float*    feats   = (float*)   alloc((size_t)N*HN*4);
  float*    q       = (float*)   alloc((size_t)N*HN*4);
  float*    kf      = (float*)   alloc((size_t)N*HN*4);
  float*    attn    = (float*)   alloc((size_t)E*4);
  float*    scores  = (float*)   alloc((size_t)E*4);
  unsigned* rowmax  = (unsigned*)alloc((size_t)N*4);
  float*    rowsum  = (float*)   alloc((size_t)N*4);
  int*      cnt     = (int*)     alloc((size_t)N*4);
  int*      ptrb    = (int*)     alloc((size_t)(N+1)*4);
  int*      fill    = (int*)     alloc((size_t)N*4);
  int*      csr_col = (int*)     alloc((size_t)E*4);
  float*    csr_val = (float*)   alloc((size_t)E*4);
  int*      knncols = (int*)     alloc((size_t)N*KNN*4);
  float*    sq      = (float*)   alloc((size_t)N*4);
  int*      flag    = (int*)     alloc(256);

  // zero / init scratch (ws is poisoned before every call)
  hipMemsetAsync(WORK,   0,    NN * 4, stream);
  hipMemsetAsync(minu,   0xFF, (size_t)N*HN*4, stream);
  hipMemsetAsync(rowmax, 0,    (size_t)N*4, stream);
  hipMemsetAsync(rowsum, 0,    (size_t)N*4, stream);
  hipMemsetAsync(cnt,    0,    (size_t)N*4, stream);
  hipMemsetAsync(fill,   0,    (size_t)N*4, stream);

  k_flag<<<1, 256, 0, stream>>>(ei, flag, N);
  k_sq<<<(N + 255)/256, 256, 0, stream>>>(x, sq, N);
  k_knn<<<N, 256, 0, stream>>>(x, sq, knncols, N);
  k_y<<<(N*HN + 255)/256, 256, 0, stream>>>(x, Wt, y, N);

  int extTot = (E + N*KNN) * HN;
  k_minedge<<<(extTot + 255)/256, 256, 0, stream>>>(ei, flag, knncols, y, minu, E, N);
  k_agg<<<(N*HN + 255)/256, 256, 0, stream>>>(y, bt, minu, N);
  k_feats<<<(N*HN + 255)/256, 256, 0, stream>>>((const float*)minu, Wp, bp, feats, N);
  k_qk<<<(N*HN + 255)/256, 256, 0, stream>>>(feats, Wq, Wk, q, kf, N);

  k_attn<<<(E + 255)/256, 256, 0, stream>>>(ei, flag, q, kf, attn, rowmax, cnt, E);
  k_scan<<<1, 1024, 0, stream>>>(cnt, ptrb, N);
  k_exp<<<(E + 255)/256, 256, 0, stream>>>(ei, flag, attn, rowmax, scores, rowsum, E);
  k_csr<<<(E + 255)/256, 256, 0, stream>>>(ei, flag, scores, rowsum, ptrb, fill,
                                           csr_col, csr_val, WORK, E, N);

  // V = S @ A^T  -> d_out (temp)
  k_spmm<<<N, 256, 0, stream>>>(ptrb, csr_col, csr_val, WORK, out, N);
  // U = V^T -> WORK (A^T no longer needed)
  dim3 trb(32, 8), trg(N/32, N/32);
  k_tr<<<trg, trb, 0, stream>>>(out, WORK, N);
  // A_s = S @ U -> d_out
  k_spmm<<<N, 256, 0, stream>>>(ptrb, csr_col, csr_val, WORK, out, N);
}

// Round 3
// 433.708 us; speedup vs baseline: 1.5355x; 1.5355x over previous
//
#include <hip/hip_runtime.h>
#include <math.h>

#define HN 64
#define KNN 15

__device__ __forceinline__ unsigned fenc(float f){
  unsigned u = __float_as_uint(f);
  return (u & 0x80000000u) ? ~u : (u | 0x80000000u);
}
__device__ __forceinline__ float fdec(unsigned u){
  return (u & 0x80000000u) ? __uint_as_float(u & 0x7fffffffu) : __uint_as_float(~u);
}

// Detect whether edge_index is stored as int64 (reference dtype) or int32.
__global__ void k_flag(const void* ei, int* flag, int n){
  __shared__ int ok[256];
  int t = threadIdx.x;
  long long v = ((const long long*)ei)[t];
  ok[t] = (v >= 0 && v < (long long)n) ? 1 : 0;
  __syncthreads();
  for (int off = 128; off > 0; off >>= 1){
    if (t < off) ok[t] &= ok[t + off];
    __syncthreads();
  }
  if (t == 0) *flag = ok[0];
}

__device__ __forceinline__ void edge_rc(const void* ei, int is64, int E, int e, int& r, int& c){
  if (is64){
    r = (int)((const long long*)ei)[e];
    c = (int)((const long long*)ei)[E + e];
  } else {
    r = ((const int*)ei)[e];
    c = ((const int*)ei)[E + e];
  }
}

__global__ void k_sq(const float* __restrict__ x, float* __restrict__ sq, int n){
  int i = blockIdx.x * 256 + threadIdx.x;
  if (i >= n) return;
  float a = x[i*3], b = x[i*3+1], c = x[i*3+2];
  sq[i] = a*a + b*b + c*c;
}

// Block per node: full-N distance row in LDS, 15 iterative argmins (index tie-break).
__global__ void k_knn(const float* __restrict__ x, const float* __restrict__ sq,
                      int* __restrict__ knn_cols, int n){
  __shared__ float d2s[4096];
  __shared__ float rv[256];
  __shared__ int   ri[256];
  int i = blockIdx.x;
  int t = threadIdx.x;
  float xi0 = x[i*3], xi1 = x[i*3+1], xi2 = x[i*3+2];
  float sqi = sq[i];
  for (int j = t; j < n; j += 256){
    float dot = xi0*x[j*3] + xi1*x[j*3+1] + xi2*x[j*3+2];
    float d2 = (sqi - 2.0f*dot) + sq[j];
    if (j == i) d2 = INFINITY;
    d2s[j] = d2;
  }
  __syncthreads();
  for (int m = 0; m < KNN; ++m){
    float bv = INFINITY; int bi = n;
    for (int j = t; j < n; j += 256){
      float v = d2s[j];
      if (v < bv || (v == bv && j < bi)){ bv = v; bi = j; }
    }
    rv[t] = bv; ri[t] = bi;
    __syncthreads();
    for (int off = 128; off > 0; off >>= 1){
      if (t < off){
        float v2 = rv[t+off]; int i2 = ri[t+off];
        if (v2 < rv[t] || (v2 == rv[t] && i2 < ri[t])){ rv[t] = v2; ri[t] = i2; }
      }
      __syncthreads();
    }
    if (t == 0){
      knn_cols[i*KNN + m] = ri[0];
      d2s[ri[0]] = INFINITY;
    }
    __syncthreads();
  }
}

// y = x @ W_theta^T   [N,64]
__global__ void k_y(const float* __restrict__ x, const float* __restrict__ Wt,
                    float* __restrict__ y, int n){
  int gid = blockIdx.x * 256 + threadIdx.x;
  if (gid >= n * HN) return;
  int nn = gid >> 6, h = gid & 63;
  float acc = x[nn*3] * Wt[h*3] + x[nn*3+1] * Wt[h*3+1] + x[nn*3+2] * Wt[h*3+2];
  y[gid] = acc;
}

// row + column counts of the original edge list
__global__ void k_cnt(const void* ei, const int* flag, int* cnt, int* ccnt, int E){
  int e = blockIdx.x * 256 + threadIdx.x;
  if (e >= E) return;
  int r, c;
  edge_rc(ei, *flag, E, e, r, c);
  atomicAdd(&cnt[r], 1);
  atomicAdd(&ccnt[c], 1);
}

// exclusive prefix sum over 4096 counts, single block of 1024
__global__ void k_scan(const int* __restrict__ cnt, int* __restrict__ ptr, int n){
  __shared__ int part[1024];
  int t = threadIdx.x;
  int base = t * 4;
  int a0 = cnt[base], a1 = cnt[base+1], a2 = cnt[base+2], a3 = cnt[base+3];
  int s = a0 + a1 + a2 + a3;
  part[t] = s;
  __syncthreads();
  for (int off = 1; off < 1024; off <<= 1){
    int v = (t >= off) ? part[t - off] : 0;
    __syncthreads();
    part[t] += v;
    __syncthreads();
  }
  int excl = part[t] - s;
  ptr[base]   = excl;
  ptr[base+1] = excl + a0;
  ptr[base+2] = excl + a0 + a1;
  ptr[base+3] = excl + a0 + a1 + a2;
  if (t == 1023) ptr[n] = part[1023];
}

// extended CSR fill: original edges (atomic slot within row)
__global__ void k_fillo(const void* ei, const int* flag, const int* __restrict__ ptr,
                        int* __restrict__ fillo, int* __restrict__ ecol, int E){
  int e = blockIdx.x * 256 + threadIdx.x;
  if (e >= E) return;
  int r, c;
  edge_rc(ei, *flag, E, e, r, c);
  int pos = ptr[r] + KNN*r + atomicAdd(&fillo[r], 1);
  ecol[pos] = c;
}

// extended CSR fill: knn edges (deterministic slots after the originals)
__global__ void k_fillk(const int* __restrict__ ptr, const int* __restrict__ cnt,
                        const int* __restrict__ knncols, int* __restrict__ ecol, int n){
  int gid = blockIdx.x * 256 + threadIdx.x;
  if (gid >= n * KNN) return;
  int i = gid / KNN, m = gid - i * KNN;
  ecol[ptr[i] + KNN*i + cnt[i] + m] = knncols[gid];
}

// DevConv via min-distribution: agg[i][h] = y[i][h] + bt[h] - min_{c in ext-nbrs(i)} y[c][h]
// 256 threads = 4 nodes/block, lane h = feature; ecol read is wave-uniform (broadcast),
// y-row read is 64 consecutive floats (coalesced).
__global__ void k_devmin(const int* __restrict__ ptr, const int* __restrict__ ecol,
                         const float* __restrict__ y, const float* __restrict__ bt,
                         float* __restrict__ agg, int n){
  int t = threadIdx.x;
  int i = blockIdx.x * 4 + (t >> 6);
  int h = t & 63;
  int beg = ptr[i] + KNN*i;
  int end = ptr[i+1] + KNN*(i+1);
  float m = INFINITY;
  for (int idx = beg; idx < end; ++idx){
    int c = ecol[idx];
    m = fminf(m, y[c*HN + h]);
  }
  agg[i*HN + h] = y[i*HN + h] + bt[h] - m;
}

// fused: feats = agg@Wp^T+bp (to LDS), then q=feats@Wq^T, kf=feats@Wk^T
__global__ void k_fqk(const float* __restrict__ agg, const float* __restrict__ Wp,
                      const float* __restrict__ bp, const float* __restrict__ Wq,
                      const float* __restrict__ Wk, float* __restrict__ q,
                      float* __restrict__ kf, int n){
  __shared__ float sag[256];
  __shared__ float sft[256];
  int t = threadIdx.x;
  int nb = blockIdx.x * 4;
  sag[t] = agg[(size_t)nb*HN + t];
  __syncthreads();
  int nn = t >> 6, h = t & 63;
  float acc = bp[h];
  #pragma unroll 8
  for (int c = 0; c < HN; ++c) acc += sag[nn*HN + c] * Wp[h*HN + c];
  sft[t] = acc;
  __syncthreads();
  float aq = 0.f, ak = 0.f;
  #pragma unroll 8
  for (int c = 0; c < HN; ++c){
    float f = sft[nn*HN + c];
    aq += f * Wq[h*HN + c];
    ak += f * Wk[h*HN + c];
  }
  q[(size_t)nb*HN + t] = aq;
  kf[(size_t)nb*HN + t] = ak;
}

// attn[e] = dot64(q[row], kf[col]) ; rowmax via encoded atomicMax
__global__ void k_attn(const void* ei, const int* flag, const float* __restrict__ q,
                       const float* __restrict__ kf, float* __restrict__ attn,
                       unsigned* __restrict__ rowmax, int E){
  int e = blockIdx.x * 256 + threadIdx.x;
  if (e >= E) return;
  int r, c;
  edge_rc(ei, *flag, E, e, r, c);
  const float4* qr = (const float4*)(q + r*HN);
  const float4* kc = (const float4*)(kf + c*HN);
  float acc = 0.f;
  #pragma unroll
  for (int m = 0; m < HN/4; ++m){
    float4 a = qr[m], b = kc[m];
    acc += a.x*b.x + a.y*b.y + a.z*b.z + a.w*b.w;
  }
  attn[e] = acc;
  atomicMax(&rowmax[r], fenc(acc));
}

__global__ void k_exp(const void* ei, const int* flag, const float* __restrict__ attn,
                      const unsigned* __restrict__ rowmax, float* __restrict__ scores,
                      float* __restrict__ rowsum, int E){
  int e = blockIdx.x * 256 + threadIdx.x;
  if (e >= E) return;
  int r, c;
  edge_rc(ei, *flag, E, e, r, c);
  float ex = expf(attn[e] - fdec(rowmax[r]));
  scores[e] = ex;
  atomicAdd(&rowsum[r], ex);
}

// Fill CSR of S (by row) and CSC of S (by col, packed (row, val) int2)
__global__ void k_csr2(const void* ei, const int* flag, const float* __restrict__ scores,
                       const float* __restrict__ rowsum, const int* __restrict__ ptr,
                       const int* __restrict__ cptr, int* __restrict__ fill2,
                       int* __restrict__ cfill, int* __restrict__ scol,
                       float* __restrict__ sval, int2* __restrict__ csp, int E){
  int e = blockIdx.x * 256 + threadIdx.x;
  if (e >= E) return;
  int r, c;
  edge_rc(ei, *flag, E, e, r, c);
  float v = scores[e] / rowsum[r];
  int p1 = ptr[r] + atomicAdd(&fill2[r], 1);
  scol[p1] = c;
  sval[p1] = v;
  int p2 = cptr[c] + atomicAdd(&cfill[c], 1);
  csp[p2] = make_int2(r, __float_as_int(v));
}

// A_s row i: 3-hop sparse walk S->A->S^T accumulated in a 16KB LDS dense row.
// A shares the CSR pattern of S with values == 1, so A-row(k) = CSR row k cols.
__global__ void __launch_bounds__(256) k_prod(
    const int* __restrict__ ptr, const int* __restrict__ scol,
    const float* __restrict__ sval, const int* __restrict__ cptr,
    const int2* __restrict__ csp, float* __restrict__ out, int n){
  __shared__ float orow[4096];
  __shared__ int   sk[64];
  __shared__ float sv[64];
  __shared__ int   slen[64];
  __shared__ int   spre[65];
  int i = blockIdx.x, t = threadIdx.x;
  for (int j = t; j < n; j += 256) orow[j] = 0.f;
  int beg = ptr[i], len = ptr[i+1] - beg;
  for (int pc = 0; pc < len; pc += 64){
    __syncthreads();                       // orow zero / prev chunk done
    int pn = min(64, len - pc);
    if (t < pn){
      int k = scol[beg + pc + t];
      sk[t] = k;
      sv[t] = sval[beg + pc + t];
      slen[t] = ptr[k+1] - ptr[k];
    }
    __syncthreads();
    if (t == 0){
      int s = 0;
      for (int p = 0; p < pn; ++p){ spre[p] = s; s += slen[p]; }
      spre[pn] = s;
    }
    __syncthreads();
    int Q = spre[pn];
    for (int idx = t; idx < Q; idx += 256){
      int lo = 0, hi = pn - 1;
      while (lo < hi){
        int mid = (lo + hi + 1) >> 1;
        if (spre[mid] <= idx) lo = mid; else hi = mid - 1;
      }
      int k = sk[lo];
      float v = sv[lo];
      int qq = ptr[k] + (idx - spre[lo]);
      int l = scol[qq];
      int rb = cptr[l], re = cptr[l+1];
      for (int r = rb; r < re; ++r){
        int2 e2 = csp[r];
        atomicAdd(&orow[e2.x], v * __int_as_float(e2.y));
      }
    }
  }
  __syncthreads();
  for (int j = t; j < n; j += 256) out[(size_t)i * n + j] = orow[j];
}

extern "C" void kernel_launch(void* const* d_in, const int* in_sizes, int n_in,
                              void* d_out, int out_size, void* d_ws, size_t ws_size,
                              hipStream_t stream) {
  const float* x   = (const float*)d_in[0];
  const void*  ei  = d_in[1];
  const float* Wt  = (const float*)d_in[2];
  const float* bt  = (const float*)d_in[3];
  const float* Wp  = (const float*)d_in[4];
  const float* bp  = (const float*)d_in[5];
  const float* Wq  = (const float*)d_in[6];
  const float* Wk  = (const float*)d_in[7];
  float* out = (float*)d_out;

  const int N = in_sizes[0] / 3;         // 4096
  const int E = in_sizes[1] / 2;         // 65536

  char* p = (char*)d_ws;
  auto alloc = [&](size_t bytes) -> void* {
    void* r = (void*)p;
    p += (bytes + 255) & ~(size_t)255;
    return r;
  };
  // counters block (zeroed with ONE memset): cnt, ccnt, fillo, fill2, cfill, rowmax, rowsum
  int*      ctr     = (int*)     alloc((size_t)7*N*4);
  int*      cnt     = ctr;
  int*      ccnt    = ctr + N;
  int*      fillo   = ctr + 2*N;
  int*      fill2   = ctr + 3*N;
  int*      cfill   = ctr + 4*N;
  unsigned* rowmax  = (unsigned*)(ctr + 5*N);
  float*    rowsum  = (float*)   (ctr + 6*N);

  float*    y       = (float*)   alloc((size_t)N*HN*4);
  float*    agg     = (float*)   alloc((size_t)N*HN*4);
  float*    q       = (float*)   alloc((size_t)N*HN*4);
  float*    kf      = (float*)   alloc((size_t)N*HN*4);
  float*    attn    = (float*)   alloc((size_t)E*4);
  float*    scores  = (float*)   alloc((size_t)E*4);
  int*      ptrb    = (int*)     alloc((size_t)(N+1)*4);
  int*      cptrb   = (int*)     alloc((size_t)(N+1)*4);
  int*      ecol    = (int*)     alloc((size_t)(E + N*KNN)*4);
  int*      scol    = (int*)     alloc((size_t)E*4);
  float*    sval    = (float*)   alloc((size_t)E*4);
  int2*     csp     = (int2*)    alloc((size_t)E*8);
  int*      knncols = (int*)     alloc((size_t)N*KNN*4);
  float*    sq      = (float*)   alloc((size_t)N*4);
  int*      flag    = (int*)     alloc(256);

  hipMemsetAsync(ctr, 0, (size_t)7*N*4, stream);

  k_flag<<<1, 256, 0, stream>>>(ei, flag, N);
  k_sq<<<(N + 255)/256, 256, 0, stream>>>(x, sq, N);
  k_knn<<<N, 256, 0, stream>>>(x, sq, knncols, N);
  k_y<<<(N*HN + 255)/256, 256, 0, stream>>>(x, Wt, y, N);

  k_cnt<<<(E + 255)/256, 256, 0, stream>>>(ei, flag, cnt, ccnt, E);
  k_scan<<<1, 1024, 0, stream>>>(cnt, ptrb, N);
  k_scan<<<1, 1024, 0, stream>>>(ccnt, cptrb, N);

  k_fillo<<<(E + 255)/256, 256, 0, stream>>>(ei, flag, ptrb, fillo, ecol, E);
  k_fillk<<<(N*KNN + 255)/256, 256, 0, stream>>>(ptrb, cnt, knncols, ecol, N);

  k_devmin<<<N/4, 256, 0, stream>>>(ptrb, ecol, y, bt, agg, N);
  k_fqk<<<N/4, 256, 0, stream>>>(agg, Wp, bp, Wq, Wk, q, kf, N);

  k_attn<<<(E + 255)/256, 256, 0, stream>>>(ei, flag, q, kf, attn, rowmax, E);
  k_exp<<<(E + 255)/256, 256, 0, stream>>>(ei, flag, attn, rowmax, scores, rowsum, E);
  k_csr2<<<(E + 255)/256, 256, 0, stream>>>(ei, flag, scores, rowsum, ptrb, cptrb,
                                            fill2, cfill, scol, sval, csp, E);

  k_prod<<<N, 256, 0, stream>>>(ptrb, scol, sval, cptrb, csp, out, N);
}

// Round 4
// 328.432 us; speedup vs baseline: 2.0277x; 1.3205x over previous
//
#include <hip/hip_runtime.h>
#include <math.h>

#define HN 64
#define KNN 15

__device__ __forceinline__ unsigned fenc(float f){
  unsigned u = __float_as_uint(f);
  return (u & 0x80000000u) ? ~u : (u | 0x80000000u);
}
__device__ __forceinline__ float fdec(unsigned u){
  return (u & 0x80000000u) ? __uint_as_float(u & 0x7fffffffu) : __uint_as_float(~u);
}

__device__ __forceinline__ unsigned long long u64min(unsigned long long a, unsigned long long b){
  return a < b ? a : b;
}
__device__ __forceinline__ unsigned long long shfl_xor_u64(unsigned long long v, int mask){
  unsigned lo = (unsigned)v, hi = (unsigned)(v >> 32);
  lo = __shfl_xor((int)lo, mask, 64);
  hi = __shfl_xor((int)hi, mask, 64);
  return ((unsigned long long)hi << 32) | lo;
}

// Detect whether edge_index is stored as int64 (reference dtype) or int32.
__global__ void k_flag(const void* ei, int* flag, int n){
  __shared__ int ok[256];
  int t = threadIdx.x;
  long long v = ((const long long*)ei)[t];
  ok[t] = (v >= 0 && v < (long long)n) ? 1 : 0;
  __syncthreads();
  for (int off = 128; off > 0; off >>= 1){
    if (t < off) ok[t] &= ok[t + off];
    __syncthreads();
  }
  if (t == 0) *flag = ok[0];
}

__device__ __forceinline__ void edge_rc(const void* ei, int is64, int E, int e, int& r, int& c){
  if (is64){
    r = (int)((const long long*)ei)[e];
    c = (int)((const long long*)ei)[E + e];
  } else {
    r = ((const int*)ei)[e];
    c = ((const int*)ei)[E + e];
  }
}

// kNN: phase 1 = per-thread min over 16 strided candidates (keys in LDS),
// phase 2 = single-wave barrier-free 15x extraction via shfl_xor u64 min-reduce.
__global__ void __launch_bounds__(256) k_knn(const float* __restrict__ x,
                                             int* __restrict__ knn_cols, int n){
  __shared__ unsigned denc[4096];
  __shared__ unsigned long long mk[256];
  int i = blockIdx.x, t = threadIdx.x;
  float xi0 = x[i*3], xi1 = x[i*3+1], xi2 = x[i*3+2];
  float sqi = xi0*xi0 + xi1*xi1 + xi2*xi2;
  unsigned long long best = ~0ULL;
  #pragma unroll
  for (int m = 0; m < 16; ++m){
    int j = t + 256*m;
    float a = x[j*3], b = x[j*3+1], c = x[j*3+2];
    float sqj = a*a + b*b + c*c;
    float dot = xi0*a + xi1*b + xi2*c;
    float d2 = (sqi - 2.0f*dot) + sqj;
    unsigned e = (j == i) ? 0xFFFFFFFFu : fenc(d2);
    denc[j] = e;
    unsigned long long key = ((unsigned long long)e << 32) | (unsigned)j;
    best = u64min(best, key);
  }
  mk[t] = best;
  __syncthreads();
  if (t >= 64) return;          // no further barriers; wave 0 finishes alone
  unsigned long long k0 = mk[t], k1 = mk[t+64], k2 = mk[t+128], k3 = mk[t+192];
  for (int m = 0; m < KNN; ++m){
    unsigned long long mm = u64min(u64min(k0, k1), u64min(k2, k3));
    #pragma unroll
    for (int off = 1; off < 64; off <<= 1)
      mm = u64min(mm, shfl_xor_u64(mm, off));
    int j = (int)(mm & 0xFFFFFFFFu);
    if (t == 0) knn_cols[i*KNN + m] = j;
    if ((j & 63) == t){
      int slot = j & 255;
      denc[j] = 0xFFFFFFFFu;
      unsigned long long nb = ~0ULL;
      #pragma unroll
      for (int m2 = 0; m2 < 16; ++m2){
        int jj = slot + 256*m2;
        unsigned long long key = ((unsigned long long)denc[jj] << 32) | (unsigned)jj;
        nb = u64min(nb, key);
      }
      int kreg = (j >> 6) & 3;
      if (kreg == 0) k0 = nb; else if (kreg == 1) k1 = nb;
      else if (kreg == 2) k2 = nb; else k3 = nb;
    }
  }
}

// y = x @ W_theta^T   [N,64]
__global__ void k_y(const float* __restrict__ x, const float* __restrict__ Wt,
                    float* __restrict__ y, int n){
  int gid = blockIdx.x * 256 + threadIdx.x;
  if (gid >= n * HN) return;
  int nn = gid >> 6, h = gid & 63;
  float acc = x[nn*3] * Wt[h*3] + x[nn*3+1] * Wt[h*3+1] + x[nn*3+2] * Wt[h*3+2];
  y[gid] = acc;
}

// row + column counts of the original edge list
__global__ void k_cnt(const void* ei, const int* flag, int* cnt, int* ccnt, int E){
  int e = blockIdx.x * 256 + threadIdx.x;
  if (e >= E) return;
  int r, c;
  edge_rc(ei, *flag, E, e, r, c);
  atomicAdd(&cnt[r], 1);
  atomicAdd(&ccnt[c], 1);
}

// exclusive prefix sum over 4096 counts, single block of 1024
__global__ void k_scan(const int* __restrict__ cnt, int* __restrict__ ptr, int n){
  __shared__ int part[1024];
  int t = threadIdx.x;
  int base = t * 4;
  int a0 = cnt[base], a1 = cnt[base+1], a2 = cnt[base+2], a3 = cnt[base+3];
  int s = a0 + a1 + a2 + a3;
  part[t] = s;
  __syncthreads();
  for (int off = 1; off < 1024; off <<= 1){
    int v = (t >= off) ? part[t - off] : 0;
    __syncthreads();
    part[t] += v;
    __syncthreads();
  }
  int excl = part[t] - s;
  ptr[base]   = excl;
  ptr[base+1] = excl + a0;
  ptr[base+2] = excl + a0 + a1;
  ptr[base+3] = excl + a0 + a1 + a2;
  if (t == 1023) ptr[n] = part[1023];
}

// extended CSR fill: original edges (atomic slot within row)
__global__ void k_fillo(const void* ei, const int* flag, const int* __restrict__ ptr,
                        int* __restrict__ fillo, int* __restrict__ ecol, int E){
  int e = blockIdx.x * 256 + threadIdx.x;
  if (e >= E) return;
  int r, c;
  edge_rc(ei, *flag, E, e, r, c);
  int pos = ptr[r] + KNN*r + atomicAdd(&fillo[r], 1);
  ecol[pos] = c;
}

// extended CSR fill: knn edges (deterministic slots after the originals)
__global__ void k_fillk(const int* __restrict__ ptr, const int* __restrict__ cnt,
                        const int* __restrict__ knncols, int* __restrict__ ecol, int n){
  int gid = blockIdx.x * 256 + threadIdx.x;
  if (gid >= n * KNN) return;
  int i = gid / KNN, m = gid - i * KNN;
  ecol[ptr[i] + KNN*i + cnt[i] + m] = knncols[gid];
}

// DevConv via min-distribution: agg[i][h] = y[i][h] + bt[h] - min_{c in ext-nbrs(i)} y[c][h]
__global__ void k_devmin(const int* __restrict__ ptr, const int* __restrict__ ecol,
                         const float* __restrict__ y, const float* __restrict__ bt,
                         float* __restrict__ agg, int n){
  int t = threadIdx.x;
  int i = blockIdx.x * 4 + (t >> 6);
  int h = t & 63;
  int beg = ptr[i] + KNN*i;
  int end = ptr[i+1] + KNN*(i+1);
  float m = INFINITY;
  for (int idx = beg; idx < end; ++idx){
    int c = ecol[idx];
    m = fminf(m, y[c*HN + h]);
  }
  agg[i*HN + h] = y[i*HN + h] + bt[h] - m;
}

// fused: feats = agg@Wp^T+bp (to LDS), then q=feats@Wq^T, kf=feats@Wk^T
__global__ void k_fqk(const float* __restrict__ agg, const float* __restrict__ Wp,
                      const float* __restrict__ bp, const float* __restrict__ Wq,
                      const float* __restrict__ Wk, float* __restrict__ q,
                      float* __restrict__ kf, int n){
  __shared__ float sag[256];
  __shared__ float sft[256];
  int t = threadIdx.x;
  int nb = blockIdx.x * 4;
  sag[t] = agg[(size_t)nb*HN + t];
  __syncthreads();
  int nn = t >> 6, h = t & 63;
  float acc = bp[h];
  #pragma unroll 8
  for (int c = 0; c < HN; ++c) acc += sag[nn*HN + c] * Wp[h*HN + c];
  sft[t] = acc;
  __syncthreads();
  float aq = 0.f, ak = 0.f;
  #pragma unroll 8
  for (int c = 0; c < HN; ++c){
    float f = sft[nn*HN + c];
    aq += f * Wq[h*HN + c];
    ak += f * Wk[h*HN + c];
  }
  q[(size_t)nb*HN + t] = aq;
  kf[(size_t)nb*HN + t] = ak;
}

// attn[e] = dot64(q[row], kf[col]) ; rowmax via encoded atomicMax
__global__ void k_attn(const void* ei, const int* flag, const float* __restrict__ q,
                       const float* __restrict__ kf, float* __restrict__ attn,
                       unsigned* __restrict__ rowmax, int E){
  int e = blockIdx.x * 256 + threadIdx.x;
  if (e >= E) return;
  int r, c;
  edge_rc(ei, *flag, E, e, r, c);
  const float4* qr = (const float4*)(q + r*HN);
  const float4* kc = (const float4*)(kf + c*HN);
  float acc = 0.f;
  #pragma unroll
  for (int m = 0; m < HN/4; ++m){
    float4 a = qr[m], b = kc[m];
    acc += a.x*b.x + a.y*b.y + a.z*b.z + a.w*b.w;
  }
  attn[e] = acc;
  atomicMax(&rowmax[r], fenc(acc));
}

__global__ void k_exp(const void* ei, const int* flag, const float* __restrict__ attn,
                      const unsigned* __restrict__ rowmax, float* __restrict__ scores,
                      float* __restrict__ rowsum, int E){
  int e = blockIdx.x * 256 + threadIdx.x;
  if (e >= E) return;
  int r, c;
  edge_rc(ei, *flag, E, e, r, c);
  float ex = expf(attn[e] - fdec(rowmax[r]));
  scores[e] = ex;
  atomicAdd(&rowsum[r], ex);
}

// Fill CSR of S (by row) and CSC of S (by col, packed (row, val) int2)
__global__ void k_csr2(const void* ei, const int* flag, const float* __restrict__ scores,
                       const float* __restrict__ rowsum, const int* __restrict__ ptr,
                       const int* __restrict__ cptr, int* __restrict__ fill2,
                       int* __restrict__ cfill, int* __restrict__ scol,
                       float* __restrict__ sval, int2* __restrict__ csp, int E){
  int e = blockIdx.x * 256 + threadIdx.x;
  if (e >= E) return;
  int r, c;
  edge_rc(ei, *flag, E, e, r, c);
  float v = scores[e] / rowsum[r];
  int p1 = ptr[r] + atomicAdd(&fill2[r], 1);
  scol[p1] = c;
  sval[p1] = v;
  int p2 = cptr[c] + atomicAdd(&cfill[c], 1);
  csp[p2] = make_int2(r, __float_as_int(v));
}

// A_s row i: 3-hop sparse walk S->A->S^T accumulated in a 16KB LDS dense row.
__global__ void __launch_bounds__(256) k_prod(
    const int* __restrict__ ptr, const int* __restrict__ scol,
    const float* __restrict__ sval, const int* __restrict__ cptr,
    const int2* __restrict__ csp, float* __restrict__ out, int n){
  __shared__ float orow[4096];
  __shared__ int   sk[64];
  __shared__ float sv[64];
  __shared__ int   slen[64];
  __shared__ int   spre[65];
  int i = blockIdx.x, t = threadIdx.x;
  for (int j = t; j < n; j += 256) orow[j] = 0.f;
  int beg = ptr[i], len = ptr[i+1] - beg;
  for (int pc = 0; pc < len; pc += 64){
    __syncthreads();
    int pn = min(64, len - pc);
    if (t < pn){
      int k = scol[beg + pc + t];
      sk[t] = k;
      sv[t] = sval[beg + pc + t];
      slen[t] = ptr[k+1] - ptr[k];
    }
    __syncthreads();
    if (t == 0){
      int s = 0;
      for (int p = 0; p < pn; ++p){ spre[p] = s; s += slen[p]; }
      spre[pn] = s;
    }
    __syncthreads();
    int Q = spre[pn];
    for (int idx = t; idx < Q; idx += 256){
      int lo = 0, hi = pn - 1;
      while (lo < hi){
        int mid = (lo + hi + 1) >> 1;
        if (spre[mid] <= idx) lo = mid; else hi = mid - 1;
      }
      int k = sk[lo];
      float v = sv[lo];
      int qq = ptr[k] + (idx - spre[lo]);
      int l = scol[qq];
      int rb = cptr[l], re = cptr[l+1];
      for (int r = rb; r < re; ++r){
        int2 e2 = csp[r];
        atomicAdd(&orow[e2.x], v * __int_as_float(e2.y));
      }
    }
  }
  __syncthreads();
  for (int j = t; j < n; j += 256) out[(size_t)i * n + j] = orow[j];
}

extern "C" void kernel_launch(void* const* d_in, const int* in_sizes, int n_in,
                              void* d_out, int out_size, void* d_ws, size_t ws_size,
                              hipStream_t stream) {
  const float* x   = (const float*)d_in[0];
  const void*  ei  = d_in[1];
  const float* Wt  = (const float*)d_in[2];
  const float* bt  = (const float*)d_in[3];
  const float* Wp  = (const float*)d_in[4];
  const float* bp  = (const float*)d_in[5];
  const float* Wq  = (const float*)d_in[6];
  const float* Wk  = (const float*)d_in[7];
  float* out = (float*)d_out;

  const int N = in_sizes[0] / 3;         // 4096
  const int E = in_sizes[1] / 2;         // 65536

  char* p = (char*)d_ws;
  auto alloc = [&](size_t bytes) -> void* {
    void* r = (void*)p;
    p += (bytes + 255) & ~(size_t)255;
    return r;
  };
  int*      ctr     = (int*)     alloc((size_t)7*N*4);
  int*      cnt     = ctr;
  int*      ccnt    = ctr + N;
  int*      fillo   = ctr + 2*N;
  int*      fill2   = ctr + 3*N;
  int*      cfill   = ctr + 4*N;
  unsigned* rowmax  = (unsigned*)(ctr + 5*N);
  float*    rowsum  = (float*)   (ctr + 6*N);

  float*    y       = (float*)   alloc((size_t)N*HN*4);
  float*    agg     = (float*)   alloc((size_t)N*HN*4);
  float*    q       = (float*)   alloc((size_t)N*HN*4);
  float*    kf      = (float*)   alloc((size_t)N*HN*4);
  float*    attn    = (float*)   alloc((size_t)E*4);
  float*    scores  = (float*)   alloc((size_t)E*4);
  int*      ptrb    = (int*)     alloc((size_t)(N+1)*4);
  int*      cptrb   = (int*)     alloc((size_t)(N+1)*4);
  int*      ecol    = (int*)     alloc((size_t)(E + N*KNN)*4);
  int*      scol    = (int*)     alloc((size_t)E*4);
  float*    sval    = (float*)   alloc((size_t)E*4);
  int2*     csp     = (int2*)    alloc((size_t)E*8);
  int*      knncols = (int*)     alloc((size_t)N*KNN*4);
  int*      flag    = (int*)     alloc(256);

  hipMemsetAsync(ctr, 0, (size_t)7*N*4, stream);

  k_flag<<<1, 256, 0, stream>>>(ei, flag, N);
  k_knn<<<N, 256, 0, stream>>>(x, knncols, N);
  k_y<<<(N*HN + 255)/256, 256, 0, stream>>>(x, Wt, y, N);

  k_cnt<<<(E + 255)/256, 256, 0, stream>>>(ei, flag, cnt, ccnt, E);
  k_scan<<<1, 1024, 0, stream>>>(cnt, ptrb, N);
  k_scan<<<1, 1024, 0, stream>>>(ccnt, cptrb, N);

  k_fillo<<<(E + 255)/256, 256, 0, stream>>>(ei, flag, ptrb, fillo, ecol, E);
  k_fillk<<<(N*KNN + 255)/256, 256, 0, stream>>>(ptrb, cnt, knncols, ecol, N);

  k_devmin<<<N/4, 256, 0, stream>>>(ptrb, ecol, y, bt, agg, N);
  k_fqk<<<N/4, 256, 0, stream>>>(agg, Wp, bp, Wq, Wk, q, kf, N);

  k_attn<<<(E + 255)/256, 256, 0, stream>>>(ei, flag, q, kf, attn, rowmax, E);
  k_exp<<<(E + 255)/256, 256, 0, stream>>>(ei, flag, attn, rowmax, scores, rowsum, E);
  k_csr2<<<(E + 255)/256, 256, 0, stream>>>(ei, flag, scores, rowsum, ptrb, cptrb,
                                            fill2, cfill, scol, sval, csp, E);

  k_prod<<<N, 256, 0, stream>>>(ptrb, scol, sval, cptrb, csp, out, N);
}

// Round 5
// 297.260 us; speedup vs baseline: 2.2404x; 1.1049x over previous
//
#include <hip/hip_runtime.h>
#include <math.h>

#define HN 64
#define KNN 15

__device__ __forceinline__ unsigned fenc(float f){
  unsigned u = __float_as_uint(f);
  return (u & 0x80000000u) ? ~u : (u | 0x80000000u);
}

__device__ __forceinline__ unsigned long long u64min(unsigned long long a, unsigned long long b){
  return a < b ? a : b;
}
__device__ __forceinline__ unsigned long long shfl_xor_u64(unsigned long long v, int mask){
  unsigned lo = (unsigned)v, hi = (unsigned)(v >> 32);
  lo = __shfl_xor((int)lo, mask, 64);
  hi = __shfl_xor((int)hi, mask, 64);
  return ((unsigned long long)hi << 32) | lo;
}

// Per-wave int64-vs-int32 edge detection + read. Row-half load ll[e] is in-bounds
// under BOTH layouts; col-half only dereferenced when layout is int64.
__device__ __forceinline__ void edge_load(const void* ei, int E, int n, int e, int& r, int& c){
  const long long* L = (const long long*)ei;
  long long vr = L[e];
  bool ok = (vr >= 0 && vr < (long long)n);
  unsigned long long bal = __ballot(ok);
  unsigned long long act = __ballot(true);
  if (bal == act){
    r = (int)vr;
    c = (int)L[E + e];
  } else {
    const int* I = (const int*)ei;
    r = I[e];
    c = I[E + e];
  }
}

// mega: [0,nbY) y = x@Wt^T ; [nbY,nbY+nbC) edge row/col counts ; rest kNN.
__global__ void __launch_bounds__(256) k_mega(
    const float* __restrict__ x, const float* __restrict__ Wt, const void* ei,
    float* __restrict__ y, int* __restrict__ knn_cols,
    int* __restrict__ cnt, int* __restrict__ ccnt,
    int N, int E, int nbY, int nbC){
  __shared__ unsigned denc[4096];
  __shared__ unsigned long long mk[256];
  int b = blockIdx.x, t = threadIdx.x;
  if (b < nbY){
    int gid = b * 256 + t;
    if (gid < N * HN){
      int nn = gid >> 6, h = gid & 63;
      y[gid] = x[nn*3] * Wt[h*3] + x[nn*3+1] * Wt[h*3+1] + x[nn*3+2] * Wt[h*3+2];
    }
    return;
  }
  if (b < nbY + nbC){
    int e = (b - nbY) * 256 + t;
    if (e < E){
      int r, c;
      edge_load(ei, E, N, e, r, c);
      atomicAdd(&cnt[r], 1);
      atomicAdd(&ccnt[c], 1);
    }
    return;
  }
  // ---- kNN for node i ----
  int i = b - nbY - nbC;
  float xi0 = x[i*3], xi1 = x[i*3+1], xi2 = x[i*3+2];
  float sqi = xi0*xi0 + xi1*xi1 + xi2*xi2;
  unsigned long long best = ~0ULL;
  #pragma unroll
  for (int m = 0; m < 16; ++m){
    int j = t + 256*m;
    float a = x[j*3], bb = x[j*3+1], c = x[j*3+2];
    float sqj = a*a + bb*bb + c*c;
    float dot = xi0*a + xi1*bb + xi2*c;
    float d2 = (sqi - 2.0f*dot) + sqj;
    unsigned e = (j == i) ? 0xFFFFFFFFu : fenc(d2);
    denc[j] = e;
    best = u64min(best, ((unsigned long long)e << 32) | (unsigned)j);
  }
  mk[t] = best;
  __syncthreads();
  if (t >= 64) return;
  unsigned long long k0 = mk[t], k1 = mk[t+64], k2 = mk[t+128], k3 = mk[t+192];
  for (int m = 0; m < KNN; ++m){
    unsigned long long mm = u64min(u64min(k0, k1), u64min(k2, k3));
    #pragma unroll
    for (int off = 1; off < 64; off <<= 1)
      mm = u64min(mm, shfl_xor_u64(mm, off));
    int j = (int)(mm & 0xFFFFFFFFu);
    if (t == 0) knn_cols[i*KNN + m] = j;
    if ((j & 63) == t){
      int slot = j & 255;
      denc[j] = 0xFFFFFFFFu;
      unsigned long long nb = ~0ULL;
      #pragma unroll
      for (int m2 = 0; m2 < 16; ++m2){
        int jj = slot + 256*m2;
        nb = u64min(nb, ((unsigned long long)denc[jj] << 32) | (unsigned)jj);
      }
      int kreg = (j >> 6) & 3;
      if (kreg == 0) k0 = nb; else if (kreg == 1) k1 = nb;
      else if (kreg == 2) k2 = nb; else k3 = nb;
    }
  }
}

// two exclusive scans in one launch: block 0 cnt->ptr, block 1 ccnt->cptr
__global__ void k_scan2(const int* __restrict__ cnt, int* __restrict__ ptr,
                        const int* __restrict__ ccnt, int* __restrict__ cptr, int n){
  __shared__ int part[1024];
  const int* src = (blockIdx.x == 0) ? cnt : ccnt;
  int* dst = (blockIdx.x == 0) ? ptr : cptr;
  int t = threadIdx.x;
  int base = t * 4;
  int a0 = src[base], a1 = src[base+1], a2 = src[base+2], a3 = src[base+3];
  int s = a0 + a1 + a2 + a3;
  part[t] = s;
  __syncthreads();
  for (int off = 1; off < 1024; off <<= 1){
    int v = (t >= off) ? part[t - off] : 0;
    __syncthreads();
    part[t] += v;
    __syncthreads();
  }
  int excl = part[t] - s;
  dst[base]   = excl;
  dst[base+1] = excl + a0;
  dst[base+2] = excl + a0 + a1;
  dst[base+3] = excl + a0 + a1 + a2;
  if (t == 1023) dst[n] = part[1023];
}

// fused extended-CSR fill: originals (atomic slots) + knn (deterministic slots)
__global__ void k_fill(const void* ei, const int* __restrict__ ptr,
                       int* __restrict__ fillo, const int* __restrict__ cnt,
                       const int* __restrict__ knncols, int* __restrict__ ecol,
                       int N, int E, int nbE){
  int b = blockIdx.x, t = threadIdx.x;
  if (b < nbE){
    int e = b * 256 + t;
    if (e < E){
      int r, c;
      edge_load(ei, E, N, e, r, c);
      int pos = ptr[r] + KNN*r + atomicAdd(&fillo[r], 1);
      ecol[pos] = c;
    }
  } else {
    int gid = (b - nbE) * 256 + t;
    if (gid < N * KNN){
      int i = gid / KNN, m = gid - i * KNN;
      ecol[ptr[i] + KNN*i + cnt[i] + m] = knncols[gid];
    }
  }
}

// fused DevConv-min + feats + q/k projections (agg/feats live in LDS only)
__global__ void k_dev(const int* __restrict__ ptr, const int* __restrict__ ecol,
                      const float* __restrict__ y, const float* __restrict__ bt,
                      const float* __restrict__ Wp, const float* __restrict__ bp,
                      const float* __restrict__ Wq, const float* __restrict__ Wk,
                      float* __restrict__ q, float* __restrict__ kf, int n){
  __shared__ float sag[256];
  __shared__ float sft[256];
  int t = threadIdx.x;
  int i = blockIdx.x * 4 + (t >> 6);
  int h = t & 63;
  int beg = ptr[i] + KNN*i;
  int end = ptr[i+1] + KNN*(i+1);
  float m = INFINITY;
  for (int idx = beg; idx < end; ++idx)
    m = fminf(m, y[ecol[idx]*HN + h]);
  sag[t] = y[i*HN + h] + bt[h] - m;
  __syncthreads();
  int nn = t >> 6;
  float acc = bp[h];
  #pragma unroll 8
  for (int c = 0; c < HN; ++c) acc += sag[nn*HN + c] * Wp[h*HN + c];
  sft[t] = acc;
  __syncthreads();
  float aq = 0.f, ak = 0.f;
  #pragma unroll 8
  for (int c = 0; c < HN; ++c){
    float f = sft[nn*HN + c];
    aq += f * Wq[h*HN + c];
    ak += f * Wk[h*HN + c];
  }
  size_t o = (size_t)blockIdx.x * 256 + t;
  q[o] = aq;
  kf[o] = ak;
}

// row-centric attention: wave per row. dot via butterfly, register max/sum,
// writes normalized S values (CSR order = ecol order) + CSC entries.
__global__ void __launch_bounds__(256) k_rowattn(
    const int* __restrict__ ptr, const int* __restrict__ cptr,
    const int* __restrict__ ecol, const float* __restrict__ q,
    const float* __restrict__ kf, float* __restrict__ sval,
    int2* __restrict__ csp, int* __restrict__ cfill, int n){
  int t = threadIdx.x;
  int lane = t & 63;
  int r = blockIdx.x * 4 + (t >> 6);
  if (r >= n) return;
  int base = ptr[r];
  int deg = ptr[r+1] - base;
  if (deg == 0) return;
  int ebase = base + KNN*r;
  float qh = q[(size_t)r*HN + lane];
  float mx = -INFINITY;
  for (int s = 0; s < deg; ++s){
    int c = ecol[ebase + s];
    float part = qh * kf[(size_t)c*HN + lane];
    #pragma unroll
    for (int off = 1; off < 64; off <<= 1) part += __shfl_xor(part, off, 64);
    if (lane == 0) sval[base + s] = part;
    mx = fmaxf(mx, part);
  }
  float lsum = 0.f;
  for (int s = lane; s < deg; s += 64){
    float e = expf(sval[base + s] - mx);
    sval[base + s] = e;
    lsum += e;
  }
  #pragma unroll
  for (int off = 1; off < 64; off <<= 1) lsum += __shfl_xor(lsum, off, 64);
  for (int s = lane; s < deg; s += 64){
    float v = sval[base + s] / lsum;
    sval[base + s] = v;
    int c = ecol[ebase + s];
    int pos = cptr[c] + atomicAdd(&cfill[c], 1);
    csp[pos] = make_int2(r, __float_as_int(v));
  }
}

// A_s row i: wave-per-p 3-hop walk, lanes = (q-slot, r-quarter); 2 barriers total.
__global__ void __launch_bounds__(256) k_prod(
    const int* __restrict__ ptr, const int* __restrict__ cnt,
    const int* __restrict__ ecol, const float* __restrict__ sval,
    const int* __restrict__ cptr, const int2* __restrict__ csp,
    float* __restrict__ out, int n){
  __shared__ float orow[4096];
  int t = threadIdx.x;
  int lane = t & 63;
  int w = t >> 6;
  int i = blockIdx.x;
  float4 z = {0.f, 0.f, 0.f, 0.f};
  float4* o4 = (float4*)orow;
  #pragma unroll
  for (int ch = 0; ch < 4; ++ch) o4[ch*256 + t] = z;
  __syncthreads();
  int base = ptr[i];
  int len = ptr[i+1] - base;
  int ebase = base + KNN*i;
  int qs = lane >> 2, rq = lane & 3;
  for (int p = w; p < len; p += 4){
    int k = ecol[ebase + p];
    float v = sval[base + p];
    int kbase = ptr[k];
    int klen = ptr[k+1] - kbase;
    int kebase = kbase + KNN*k;
    for (int qq = qs; qq < klen; qq += 16){
      int l = ecol[kebase + qq];
      int rb = cptr[l], re = cptr[l+1];
      for (int rr = rb + rq; rr < re; rr += 4){
        int2 e2 = csp[rr];
        atomicAdd(&orow[e2.x], v * __int_as_float(e2.y));
      }
    }
  }
  __syncthreads();
  float4* dst = (float4*)(out + (size_t)i * n);
  #pragma unroll
  for (int ch = 0; ch < 4; ++ch) dst[ch*256 + t] = o4[ch*256 + t];
}

extern "C" void kernel_launch(void* const* d_in, const int* in_sizes, int n_in,
                              void* d_out, int out_size, void* d_ws, size_t ws_size,
                              hipStream_t stream) {
  const float* x   = (const float*)d_in[0];
  const void*  ei  = d_in[1];
  const float* Wt  = (const float*)d_in[2];
  const float* bt  = (const float*)d_in[3];
  const float* Wp  = (const float*)d_in[4];
  const float* bp  = (const float*)d_in[5];
  const float* Wq  = (const float*)d_in[6];
  const float* Wk  = (const float*)d_in[7];
  float* out = (float*)d_out;

  const int N = in_sizes[0] / 3;         // 4096
  const int E = in_sizes[1] / 2;         // 65536

  char* p = (char*)d_ws;
  auto alloc = [&](size_t bytes) -> void* {
    void* r = (void*)p;
    p += (bytes + 255) & ~(size_t)255;
    return r;
  };
  int*      ctr     = (int*)  alloc((size_t)4*N*4);   // cnt, ccnt, cfill, fillo
  int*      cnt     = ctr;
  int*      ccnt    = ctr + N;
  int*      cfill   = ctr + 2*N;
  int*      fillo   = ctr + 3*N;

  float*    y       = (float*)alloc((size_t)N*HN*4);
  float*    q       = (float*)alloc((size_t)N*HN*4);
  float*    kf      = (float*)alloc((size_t)N*HN*4);
  int*      ptrb    = (int*)  alloc((size_t)(N+1)*4);
  int*      cptrb   = (int*)  alloc((size_t)(N+1)*4);
  int*      ecol    = (int*)  alloc((size_t)(E + N*KNN)*4);
  float*    sval    = (float*)alloc((size_t)E*4);
  int2*     csp     = (int2*) alloc((size_t)E*8);
  int*      knncols = (int*)  alloc((size_t)N*KNN*4);

  hipMemsetAsync(ctr, 0, (size_t)4*N*4, stream);

  int nbY = (N*HN + 255)/256;            // 1024
  int nbC = (E + 255)/256;               // 256
  int nbK = (N*KNN + 255)/256;           // 240

  k_mega<<<nbY + nbC + N, 256, 0, stream>>>(x, Wt, ei, y, knncols, cnt, ccnt,
                                            N, E, nbY, nbC);
  k_scan2<<<2, 1024, 0, stream>>>(cnt, ptrb, ccnt, cptrb, N);
  k_fill<<<nbC + nbK, 256, 0, stream>>>(ei, ptrb, fillo, cnt, knncols, ecol,
                                        N, E, nbC);
  k_dev<<<N/4, 256, 0, stream>>>(ptrb, ecol, y, bt, Wp, bp, Wq, Wk, q, kf, N);
  k_rowattn<<<N/4, 256, 0, stream>>>(ptrb, cptrb, ecol, q, kf, sval, csp, cfill, N);
  k_prod<<<N, 256, 0, stream>>>(ptrb, cnt, ecol, sval, cptrb, csp, out, N);
}

// Round 6
// 291.331 us; speedup vs baseline: 2.2860x; 1.0204x over previous
//
#include <hip/hip_runtime.h>
#include <math.h>

#define HN 64
#define KNN 15

__device__ __forceinline__ unsigned fenc(float f){
  unsigned u = __float_as_uint(f);
  return (u & 0x80000000u) ? ~u : (u | 0x80000000u);
}

__device__ __forceinline__ unsigned long long u64min(unsigned long long a, unsigned long long b){
  return a < b ? a : b;
}
__device__ __forceinline__ unsigned long long shfl_xor_u64(unsigned long long v, int mask){
  unsigned lo = (unsigned)v, hi = (unsigned)(v >> 32);
  lo = __shfl_xor((int)lo, mask, 64);
  hi = __shfl_xor((int)hi, mask, 64);
  return ((unsigned long long)hi << 32) | lo;
}

// Per-wave int64-vs-int32 edge detection + read.
__device__ __forceinline__ void edge_load(const void* ei, int E, int n, int e, int& r, int& c){
  const long long* L = (const long long*)ei;
  long long vr = L[e];
  bool ok = (vr >= 0 && vr < (long long)n);
  unsigned long long bal = __ballot(ok);
  unsigned long long act = __ballot(true);
  if (bal == act){
    r = (int)vr;
    c = (int)L[E + e];
  } else {
    const int* I = (const int*)ei;
    r = I[e];
    c = I[E + e];
  }
}

// mega: [0,nbY) y = x@Wt^T ; [nbY,nbY+nbC) edge row/col counts ; rest kNN.
__global__ void __launch_bounds__(256) k_mega(
    const float* __restrict__ x, const float* __restrict__ Wt, const void* ei,
    float* __restrict__ y, int* __restrict__ knn_cols,
    int* __restrict__ cnt, int* __restrict__ ccnt,
    int N, int E, int nbY, int nbC){
  __shared__ unsigned denc[4096];
  __shared__ unsigned long long mk[256];
  int b = blockIdx.x, t = threadIdx.x;
  if (b < nbY){
    int gid = b * 256 + t;
    if (gid < N * HN){
      int nn = gid >> 6, h = gid & 63;
      y[gid] = x[nn*3] * Wt[h*3] + x[nn*3+1] * Wt[h*3+1] + x[nn*3+2] * Wt[h*3+2];
    }
    return;
  }
  if (b < nbY + nbC){
    int e = (b - nbY) * 256 + t;
    if (e < E){
      int r, c;
      edge_load(ei, E, N, e, r, c);
      atomicAdd(&cnt[r], 1);
      atomicAdd(&ccnt[c], 1);
    }
    return;
  }
  // ---- kNN for node i ----
  int i = b - nbY - nbC;
  float xi0 = x[i*3], xi1 = x[i*3+1], xi2 = x[i*3+2];
  float sqi = xi0*xi0 + xi1*xi1 + xi2*xi2;
  unsigned long long best = ~0ULL;
  #pragma unroll
  for (int m = 0; m < 16; ++m){
    int j = t + 256*m;
    float a = x[j*3], bb = x[j*3+1], c = x[j*3+2];
    float sqj = a*a + bb*bb + c*c;
    float dot = xi0*a + xi1*bb + xi2*c;
    float d2 = (sqi - 2.0f*dot) + sqj;
    unsigned e = (j == i) ? 0xFFFFFFFFu : fenc(d2);
    denc[j] = e;
    best = u64min(best, ((unsigned long long)e << 32) | (unsigned)j);
  }
  mk[t] = best;
  __syncthreads();
  if (t >= 64) return;
  unsigned long long k0 = mk[t], k1 = mk[t+64], k2 = mk[t+128], k3 = mk[t+192];
  for (int m = 0; m < KNN; ++m){
    unsigned long long mm = u64min(u64min(k0, k1), u64min(k2, k3));
    #pragma unroll
    for (int off = 1; off < 64; off <<= 1)
      mm = u64min(mm, shfl_xor_u64(mm, off));
    int j = (int)(mm & 0xFFFFFFFFu);
    if (t == 0) knn_cols[i*KNN + m] = j;
    if ((j & 63) == t){
      int slot = j & 255;
      denc[j] = 0xFFFFFFFFu;
      unsigned long long nb = ~0ULL;
      #pragma unroll
      for (int m2 = 0; m2 < 16; ++m2){
        int jj = slot + 256*m2;
        nb = u64min(nb, ((unsigned long long)denc[jj] << 32) | (unsigned)jj);
      }
      int kreg = (j >> 6) & 3;
      if (kreg == 0) k0 = nb; else if (kreg == 1) k1 = nb;
      else if (kreg == 2) k2 = nb; else k3 = nb;
    }
  }
}

// two exclusive scans in one launch; also emits packed (base,len) info tables:
// rinfo[k] = (ptr[k]+KNN*k, cnt[k])   cinfo[l] = (cptr[l], ccnt[l])
__global__ void k_scan2(const int* __restrict__ cnt, int* __restrict__ ptr,
                        const int* __restrict__ ccnt, int* __restrict__ cptr,
                        int2* __restrict__ rinfo, int2* __restrict__ cinfo, int n){
  __shared__ int part[1024];
  const int* src = (blockIdx.x == 0) ? cnt : ccnt;
  int* dst = (blockIdx.x == 0) ? ptr : cptr;
  int t = threadIdx.x;
  int base = t * 4;
  int a0 = src[base], a1 = src[base+1], a2 = src[base+2], a3 = src[base+3];
  int s = a0 + a1 + a2 + a3;
  part[t] = s;
  __syncthreads();
  for (int off = 1; off < 1024; off <<= 1){
    int v = (t >= off) ? part[t - off] : 0;
    __syncthreads();
    part[t] += v;
    __syncthreads();
  }
  int excl = part[t] - s;
  int v0 = excl, v1 = excl + a0, v2 = excl + a0 + a1, v3 = excl + a0 + a1 + a2;
  dst[base]   = v0;
  dst[base+1] = v1;
  dst[base+2] = v2;
  dst[base+3] = v3;
  if (t == 1023) dst[n] = part[1023];
  if (blockIdx.x == 0){
    rinfo[base]   = make_int2(v0 + KNN*base,     a0);
    rinfo[base+1] = make_int2(v1 + KNN*(base+1), a1);
    rinfo[base+2] = make_int2(v2 + KNN*(base+2), a2);
    rinfo[base+3] = make_int2(v3 + KNN*(base+3), a3);
  } else {
    cinfo[base]   = make_int2(v0, a0);
    cinfo[base+1] = make_int2(v1, a1);
    cinfo[base+2] = make_int2(v2, a2);
    cinfo[base+3] = make_int2(v3, a3);
  }
}

// fused extended-CSR fill: originals (atomic slots) + knn (deterministic slots)
__global__ void k_fill(const void* ei, const int* __restrict__ ptr,
                       int* __restrict__ fillo, const int* __restrict__ cnt,
                       const int* __restrict__ knncols, int* __restrict__ ecol,
                       int N, int E, int nbE){
  int b = blockIdx.x, t = threadIdx.x;
  if (b < nbE){
    int e = b * 256 + t;
    if (e < E){
      int r, c;
      edge_load(ei, E, N, e, r, c);
      int pos = ptr[r] + KNN*r + atomicAdd(&fillo[r], 1);
      ecol[pos] = c;
    }
  } else {
    int gid = (b - nbE) * 256 + t;
    if (gid < N * KNN){
      int i = gid / KNN, m = gid - i * KNN;
      ecol[ptr[i] + KNN*i + cnt[i] + m] = knncols[gid];
    }
  }
}

// fused DevConv-min + feats + q/k projections (agg/feats live in LDS only)
__global__ void k_dev(const int* __restrict__ ptr, const int* __restrict__ ecol,
                      const float* __restrict__ y, const float* __restrict__ bt,
                      const float* __restrict__ Wp, const float* __restrict__ bp,
                      const float* __restrict__ Wq, const float* __restrict__ Wk,
                      float* __restrict__ q, float* __restrict__ kf, int n){
  __shared__ float sag[256];
  __shared__ float sft[256];
  int t = threadIdx.x;
  int i = blockIdx.x * 4 + (t >> 6);
  int h = t & 63;
  int beg = ptr[i] + KNN*i;
  int end = ptr[i+1] + KNN*(i+1);
  float m = INFINITY;
  for (int idx = beg; idx < end; ++idx)
    m = fminf(m, y[ecol[idx]*HN + h]);
  sag[t] = y[i*HN + h] + bt[h] - m;
  __syncthreads();
  int nn = t >> 6;
  float acc = bp[h];
  #pragma unroll 8
  for (int c = 0; c < HN; ++c) acc += sag[nn*HN + c] * Wp[h*HN + c];
  sft[t] = acc;
  __syncthreads();
  float aq = 0.f, ak = 0.f;
  #pragma unroll 8
  for (int c = 0; c < HN; ++c){
    float f = sft[nn*HN + c];
    aq += f * Wq[h*HN + c];
    ak += f * Wk[h*HN + c];
  }
  size_t o = (size_t)blockIdx.x * 256 + t;
  q[o] = aq;
  kf[o] = ak;
}

// row-centric attention, lane-parallel over edges: lane s owns edge s (stride 64).
// Each lane computes a full 64-dot; wave reduces max/sum; writes scp (col,val)
// in CSR order and csp (row,val) in CSC order.
__global__ void __launch_bounds__(256) k_rowattn(
    const int* __restrict__ ptr, const int2* __restrict__ cinfo,
    const int* __restrict__ ecol, const float* __restrict__ q,
    const float* __restrict__ kf, float* __restrict__ sval,
    int2* __restrict__ scp, int2* __restrict__ csp,
    int* __restrict__ cfill, int n){
  int t = threadIdx.x;
  int lane = t & 63;
  int r = blockIdx.x * 4 + (t >> 6);
  if (r >= n) return;
  int base = ptr[r];
  int deg = ptr[r+1] - base;
  if (deg == 0) return;
  int ebase = base + KNN*r;
  // q row (wave-uniform, broadcast-friendly)
  float4 qv[16];
  const float4* qr = (const float4*)(q + (size_t)r*HN);
  #pragma unroll
  for (int m = 0; m < 16; ++m) qv[m] = qr[m];
  float mx = -INFINITY;
  for (int s = lane; s < deg; s += 64){
    int c = ecol[ebase + s];
    const float4* kc = (const float4*)(kf + (size_t)c*HN);
    float acc = 0.f;
    #pragma unroll
    for (int m = 0; m < 16; ++m){
      float4 b = kc[m];
      acc += qv[m].x*b.x + qv[m].y*b.y + qv[m].z*b.z + qv[m].w*b.w;
    }
    sval[base + s] = acc;
    mx = fmaxf(mx, acc);
  }
  #pragma unroll
  for (int off = 1; off < 64; off <<= 1) mx = fmaxf(mx, __shfl_xor(mx, off, 64));
  float lsum = 0.f;
  for (int s = lane; s < deg; s += 64){
    float e = expf(sval[base + s] - mx);
    sval[base + s] = e;
    lsum += e;
  }
  #pragma unroll
  for (int off = 1; off < 64; off <<= 1) lsum += __shfl_xor(lsum, off, 64);
  for (int s = lane; s < deg; s += 64){
    float v = sval[base + s] / lsum;
    int c = ecol[ebase + s];
    scp[base + s] = make_int2(c, __float_as_int(v));
    int pos = cinfo[c].x + atomicAdd(&cfill[c], 1);
    csp[pos] = make_int2(r, __float_as_int(v));
  }
}

// A_s rows 2b, 2b+1: wave-per-p 3-hop walk with packed metadata.
// 512 threads = 2 halves x 4 waves; 32KB LDS; chain: scp -> rinfo -> ecol -> cinfo -> csp.
__global__ void __launch_bounds__(512) k_prod(
    const int* __restrict__ ptr, const int2* __restrict__ scp,
    const int2* __restrict__ rinfo, const int* __restrict__ ecol,
    const int2* __restrict__ cinfo, const int2* __restrict__ csp,
    float* __restrict__ out, int n){
  __shared__ float orow[2][4096];
  int t = threadIdx.x;
  int half = t >> 8;
  int tt = t & 255;
  int lane = t & 63;
  int w = (t >> 6) & 3;
  int i = blockIdx.x * 2 + half;
  float4 z = {0.f, 0.f, 0.f, 0.f};
  float4* o4 = (float4*)orow[half];
  #pragma unroll
  for (int ch = 0; ch < 4; ++ch) o4[ch*256 + tt] = z;
  __syncthreads();
  int base = ptr[i];
  int len = ptr[i+1] - base;
  int qs = lane >> 2, rq = lane & 3;
  float* my = orow[half];
  for (int p = w; p < len; p += 4){
    int2 kv = scp[base + p];
    float v = __int_as_float(kv.y);
    int2 ri = rinfo[kv.x];
    for (int qq = qs; qq < ri.y; qq += 16){
      int l = ecol[ri.x + qq];
      int2 ci = cinfo[l];
      for (int rr = rq; rr < ci.y; rr += 4){
        int2 e2 = csp[ci.x + rr];
        atomicAdd(&my[e2.x], v * __int_as_float(e2.y));
      }
    }
  }
  __syncthreads();
  float4* dst = (float4*)(out + (size_t)i * n);
  #pragma unroll
  for (int ch = 0; ch < 4; ++ch) dst[ch*256 + tt] = o4[ch*256 + tt];
}

extern "C" void kernel_launch(void* const* d_in, const int* in_sizes, int n_in,
                              void* d_out, int out_size, void* d_ws, size_t ws_size,
                              hipStream_t stream) {
  const float* x   = (const float*)d_in[0];
  const void*  ei  = d_in[1];
  const float* Wt  = (const float*)d_in[2];
  const float* bt  = (const float*)d_in[3];
  const float* Wp  = (const float*)d_in[4];
  const float* bp  = (const float*)d_in[5];
  const float* Wq  = (const float*)d_in[6];
  const float* Wk  = (const float*)d_in[7];
  float* out = (float*)d_out;

  const int N = in_sizes[0] / 3;         // 4096
  const int E = in_sizes[1] / 2;         // 65536

  char* p = (char*)d_ws;
  auto alloc = [&](size_t bytes) -> void* {
    void* r = (void*)p;
    p += (bytes + 255) & ~(size_t)255;
    return r;
  };
  int*      ctr     = (int*)  alloc((size_t)4*N*4);   // cnt, ccnt, cfill, fillo
  int*      cnt     = ctr;
  int*      ccnt    = ctr + N;
  int*      cfill   = ctr + 2*N;
  int*      fillo   = ctr + 3*N;

  float*    y       = (float*)alloc((size_t)N*HN*4);
  float*    q       = (float*)alloc((size_t)N*HN*4);
  float*    kf      = (float*)alloc((size_t)N*HN*4);
  int*      ptrb    = (int*)  alloc((size_t)(N+1)*4);
  int*      cptrb   = (int*)  alloc((size_t)(N+1)*4);
  int2*     rinfo   = (int2*) alloc((size_t)N*8);
  int2*     cinfo   = (int2*) alloc((size_t)N*8);
  int*      ecol    = (int*)  alloc((size_t)(E + N*KNN)*4);
  float*    sval    = (float*)alloc((size_t)E*4);
  int2*     scp     = (int2*) alloc((size_t)E*8);
  int2*     csp     = (int2*) alloc((size_t)E*8);
  int*      knncols = (int*)  alloc((size_t)N*KNN*4);

  hipMemsetAsync(ctr, 0, (size_t)4*N*4, stream);

  int nbY = (N*HN + 255)/256;            // 1024
  int nbC = (E + 255)/256;               // 256
  int nbK = (N*KNN + 255)/256;           // 240

  k_mega<<<nbY + nbC + N, 256, 0, stream>>>(x, Wt, ei, y, knncols, cnt, ccnt,
                                            N, E, nbY, nbC);
  k_scan2<<<2, 1024, 0, stream>>>(cnt, ptrb, ccnt, cptrb, rinfo, cinfo, N);
  k_fill<<<nbC + nbK, 256, 0, stream>>>(ei, ptrb, fillo, cnt, knncols, ecol,
                                        N, E, nbC);
  k_dev<<<N/4, 256, 0, stream>>>(ptrb, ecol, y, bt, Wp, bp, Wq, Wk, q, kf, N);
  k_rowattn<<<N/4, 256, 0, stream>>>(ptrb, cinfo, ecol, q, kf, sval, scp, csp,
                                     cfill, N);
  k_prod<<<N/2, 512, 0, stream>>>(ptrb, scp, rinfo, ecol, cinfo, csp, out, N);
}